// Round 1
// baseline (25.147 us; speedup 1.0000x reference)
//
#include <hip/hip_runtime.h>
#include <math.h>

#define THREADS 1024

__device__ __forceinline__ void quat_to_mat(const float q[4], float R[9]) {
    float n = sqrtf(q[0]*q[0] + q[1]*q[1] + q[2]*q[2] + q[3]*q[3]);
    float w = q[0]/n, x = q[1]/n, y = q[2]/n, z = q[3]/n;
    R[0] = 1.f - 2.f*(y*y + z*z);
    R[1] = 2.f*(x*y - w*z);
    R[2] = 2.f*(x*z + w*y);
    R[3] = 2.f*(x*y + w*z);
    R[4] = 1.f - 2.f*(x*x + z*z);
    R[5] = 2.f*(y*z - w*x);
    R[6] = 2.f*(x*z - w*y);
    R[7] = 2.f*(y*z + w*x);
    R[8] = 1.f - 2.f*(x*x + y*y);
}

__global__ __launch_bounds__(THREADS) void rot_laplace_nll(
    const float* __restrict__ gt_quat,
    const float* __restrict__ mode_quat,
    const float* __restrict__ cov_tril,
    const float* __restrict__ grids,
    float* __restrict__ out, int n_total)
{
    const int b   = blockIdx.x;
    const int tid = threadIdx.x;

    // ---- precision matrix Z = (L L^T)^{-1} = L^{-T} L^{-1}, closed form 3x3 tri-inverse
    const float* L = cov_tril + b * 9;
    float a = L[0], l10 = L[3], c = L[4], d = L[6], e = L[7], f = L[8];
    float ia = 1.0f / a, ic = 1.0f / c, iff = 1.0f / f;
    float m00 = ia;
    float m10 = -l10 * ia * ic;
    float m11 = ic;
    float m20 = (l10 * e - c * d) * ia * ic * iff;
    float m21 = -e * ic * iff;
    float m22 = iff;
    float Z0 = m00*m00 + m10*m10 + m20*m20;
    float Z1 = m10*m11 + m20*m21;
    float Z2 = m20*m22;
    float Z4 = m11*m11 + m21*m21;
    float Z5 = m21*m22;
    float Z8 = m22*m22;
    float trZ = Z0 + Z4 + Z8;
    // Z symmetric -> tr(Z @ R) = flat elementwise dot(Z, R)
    float Z[9] = {Z0, Z1, Z2, Z1, Z4, Z5, Z2, Z5, Z8};

    // ---- single pass over grid: S = sum_n exp(-p)/p  (stability shift cancels analytically)
    double acc = 0.0;
    for (int n = tid; n < n_total; n += THREADS) {
        const float* G = grids + n * 9;
        float tr = 0.f;
#pragma unroll
        for (int k = 0; k < 9; ++k) tr = fmaf(Z[k], G[k], tr);
        float p = sqrtf(fmaxf(trZ - tr, 1e-8f));
        acc += (double)(expf(-p) / p);
    }

    // ---- wave (64-lane) reduce, then cross-wave via LDS
#pragma unroll
    for (int off = 32; off > 0; off >>= 1)
        acc += __shfl_down(acc, off, 64);

    __shared__ double wsum[THREADS / 64];
    const int wave = tid >> 6;
    if ((tid & 63) == 0) wsum[wave] = acc;
    __syncthreads();

    if (tid == 0) {
        double S = 0.0;
#pragma unroll
        for (int w = 0; w < THREADS / 64; ++w) S += wsum[w];

        float q0[4] = {mode_quat[b*4+0], mode_quat[b*4+1], mode_quat[b*4+2], mode_quat[b*4+3]};
        float qg[4] = {gt_quat[b*4+0],   gt_quat[b*4+1],   gt_quat[b*4+2],   gt_quat[b*4+3]};
        float R0[9], Rg[9];
        quat_to_mat(q0, R0);
        quat_to_mat(qg, Rg);

        // R_rel[i][j] = sum_k R0[k][i] * Rg[k][j]  (= R0^T @ Rg)
        // tr(Z @ R_rel) = flat dot(Z, R_rel) by symmetry of Z
        float tr = 0.f;
#pragma unroll
        for (int i = 0; i < 3; ++i) {
#pragma unroll
            for (int j = 0; j < 3; ++j) {
                float rr = R0[0*3+i]*Rg[0*3+j] + R0[1*3+i]*Rg[1*3+j] + R0[2*3+i]*Rg[2*3+j];
                tr = fmaf(Z[i*3+j], rr, tr);
            }
        }
        float power = sqrtf(fmaxf(trZ - tr, 1e-8f));
        float logF  = (float)(log(S) - log((double)n_total));
        out[b] = logF + power + logf(power);
    }
}

extern "C" void kernel_launch(void* const* d_in, const int* in_sizes, int n_in,
                              void* d_out, int out_size, void* d_ws, size_t ws_size,
                              hipStream_t stream) {
    const float* gt    = (const float*)d_in[0];
    const float* mode  = (const float*)d_in[1];
    const float* cov   = (const float*)d_in[2];
    const float* grids = (const float*)d_in[3];
    float* out = (float*)d_out;

    int bcount  = in_sizes[0] / 4;   // 256
    int n_total = in_sizes[3] / 9;   // 36864

    rot_laplace_nll<<<bcount, THREADS, 0, stream>>>(gt, mode, cov, grids, out, n_total);
}

// Round 2
// 19.006 us; speedup vs baseline: 1.3231x; 1.3231x over previous
//
#include <hip/hip_runtime.h>
#include <math.h>

#define TPB 256
#define KROT 6                 // rotations per thread (held in registers, 6 floats each)
#define BPB 8                  // batch elements per block
#define NCHUNK (TPB * KROT)    // 1536 rotations per n-tile

// returns {-Z0,-Z4,-Z8,-Z1,-Z2,-Z5, trZ} for FMA-friendly x = trZ - tr(Z R)
__device__ __forceinline__ void compute_Z_neg(const float* __restrict__ L, float zo[7]) {
    float a = L[0], l10 = L[3], c = L[4], d = L[6], e = L[7], f = L[8];
    float ia = 1.0f / a, ic = 1.0f / c, iff = 1.0f / f;
    float m00 = ia;
    float m10 = -l10 * ia * ic;
    float m11 = ic;
    float m20 = (l10 * e - c * d) * ia * ic * iff;
    float m21 = -e * ic * iff;
    float m22 = iff;
    float Z0 = m00*m00 + m10*m10 + m20*m20;
    float Z1 = m10*m11 + m20*m21;
    float Z2 = m20*m22;
    float Z4 = m11*m11 + m21*m21;
    float Z5 = m21*m22;
    float Z8 = m22*m22;
    zo[0] = -Z0; zo[1] = -Z4; zo[2] = -Z8;   // diagonal
    zo[3] = -Z1; zo[4] = -Z2; zo[5] = -Z5;   // off-diagonal (paired with G_ij+G_ji)
    zo[6] = Z0 + Z4 + Z8;                    // trZ
}

__device__ __forceinline__ void quat_to_mat(const float q[4], float R[9]) {
    float n = sqrtf(q[0]*q[0] + q[1]*q[1] + q[2]*q[2] + q[3]*q[3]);
    float w = q[0]/n, x = q[1]/n, y = q[2]/n, z = q[3]/n;
    R[0] = 1.f - 2.f*(y*y + z*z);
    R[1] = 2.f*(x*y - w*z);
    R[2] = 2.f*(x*z + w*y);
    R[3] = 2.f*(x*y + w*z);
    R[4] = 1.f - 2.f*(x*x + z*z);
    R[5] = 2.f*(y*z - w*x);
    R[6] = 2.f*(x*z - w*y);
    R[7] = 2.f*(y*z + w*x);
    R[8] = 1.f - 2.f*(x*x + y*y);
}

// K1: grid (n_tiles, B/BPB). Each block: 1536 rotations x 8 batch elements.
// Rotations live in registers (6 compressed floats each); zero per-pair memory.
__global__ __launch_bounds__(TPB) void k1_partials(
    const float* __restrict__ cov_tril,
    const float* __restrict__ grids,
    double* __restrict__ ws, int B)
{
    const int tile = blockIdx.x;
    const int bg   = blockIdx.y;
    const int tid  = threadIdx.x;

    __shared__ float zsh[BPB][8];
    __shared__ float red[TPB * 9];   // 9216 B; stride 9 -> conflict-free (2-way)

    if (tid < BPB) {
        float zo[7];
        compute_Z_neg(cov_tril + (bg * BPB + tid) * 9, zo);
#pragma unroll
        for (int j = 0; j < 7; ++j) zsh[tid][j] = zo[j];
    }

    // ---- load my 6 rotations, compress 9 -> 6 floats using Z-symmetry
    float g[KROT][6];
    const float* base = grids + (size_t)(tile * NCHUNK + tid * KROT) * 9;
#pragma unroll
    for (int k = 0; k < KROT; ++k) {
        const float* G = base + k * 9;
        float G0 = G[0], G1 = G[1], G2 = G[2], G3 = G[3], G4 = G[4];
        float G5 = G[5], G6 = G[6], G7 = G[7], G8 = G[8];
        g[k][0] = G0; g[k][1] = G4; g[k][2] = G8;
        g[k][3] = G1 + G3; g[k][4] = G2 + G6; g[k][5] = G5 + G7;
    }
    __syncthreads();

    // ---- inner: 8 b x 6 rotations, all register/LDS-broadcast operands
    float acc[BPB];
#pragma unroll
    for (int bl = 0; bl < BPB; ++bl) {
        float z0 = zsh[bl][0], z1 = zsh[bl][1], z2 = zsh[bl][2];
        float z3 = zsh[bl][3], z4 = zsh[bl][4], z5 = zsh[bl][5];
        float trZ = zsh[bl][6];
        float a0 = 0.f;
#pragma unroll
        for (int k = 0; k < KROT; ++k) {
            float x = trZ;
            x = fmaf(z0, g[k][0], x);
            x = fmaf(z1, g[k][1], x);
            x = fmaf(z2, g[k][2], x);
            x = fmaf(z3, g[k][3], x);
            x = fmaf(z4, g[k][4], x);
            x = fmaf(z5, g[k][5], x);
            x = fmaxf(x, 1e-8f);
            float r = rsqrtf(x);       // = 1/p since p = sqrt(x)
            float p = x * r;
            a0 += __expf(-p) * r;      // exp(-p)/p
        }
        acc[bl] = a0;
    }

    // ---- two-stage block reduce: [256 threads][8 b] -> 8 sums
#pragma unroll
    for (int bl = 0; bl < BPB; ++bl) red[tid * 9 + bl] = acc[bl];
    __syncthreads();

    const int bl = tid & 7;        // which b
    const int s  = tid >> 3;       // segment 0..31
    float part = 0.f;
#pragma unroll
    for (int j = 0; j < 8; ++j) part += red[(s * 8 + j) * 9 + bl];
    __syncthreads();
    red[tid] = part;               // tid == s*8+bl
    __syncthreads();

    if (tid < BPB) {
        double S = 0.0;
#pragma unroll
        for (int j = 0; j < 32; ++j) S += (double)red[j * 8 + tid];
        ws[(size_t)tile * B + bg * BPB + tid] = S;
    }
}

// K2: finalize per b: S -> logF; gt/mode quats -> power; out = logF + power + log(power)
__global__ __launch_bounds__(TPB) void k2_finalize(
    const float* __restrict__ gt_quat,
    const float* __restrict__ mode_quat,
    const float* __restrict__ cov_tril,
    const double* __restrict__ ws,
    float* __restrict__ out, int n_tiles, int n_total, int B)
{
    const int b = blockIdx.x * blockDim.x + threadIdx.x;
    if (b >= B) return;

    double S = 0.0;
    for (int t = 0; t < n_tiles; ++t) S += ws[(size_t)t * B + b];

    float zo[7];
    compute_Z_neg(cov_tril + b * 9, zo);
    float trZ = zo[6];

    float q0[4] = {mode_quat[b*4+0], mode_quat[b*4+1], mode_quat[b*4+2], mode_quat[b*4+3]};
    float qg[4] = {gt_quat[b*4+0],   gt_quat[b*4+1],   gt_quat[b*4+2],   gt_quat[b*4+3]};
    float R0[9], Rg[9];
    quat_to_mat(q0, R0);
    quat_to_mat(qg, Rg);

    // R_rel = R0^T Rg; x = trZ - tr(Z R_rel) via compressed form
    float Rr[9];
#pragma unroll
    for (int i = 0; i < 3; ++i)
#pragma unroll
        for (int j = 0; j < 3; ++j)
            Rr[i*3+j] = R0[0*3+i]*Rg[0*3+j] + R0[1*3+i]*Rg[1*3+j] + R0[2*3+i]*Rg[2*3+j];

    float x = trZ;
    x = fmaf(zo[0], Rr[0], x);
    x = fmaf(zo[1], Rr[4], x);
    x = fmaf(zo[2], Rr[8], x);
    x = fmaf(zo[3], Rr[1] + Rr[3], x);
    x = fmaf(zo[4], Rr[2] + Rr[6], x);
    x = fmaf(zo[5], Rr[5] + Rr[7], x);

    float power = sqrtf(fmaxf(x, 1e-8f));
    float logF  = (float)(log(S) - log((double)n_total));
    out[b] = logF + power + logf(power);
}

extern "C" void kernel_launch(void* const* d_in, const int* in_sizes, int n_in,
                              void* d_out, int out_size, void* d_ws, size_t ws_size,
                              hipStream_t stream) {
    const float* gt    = (const float*)d_in[0];
    const float* mode  = (const float*)d_in[1];
    const float* cov   = (const float*)d_in[2];
    const float* grids = (const float*)d_in[3];
    float* out = (float*)d_out;

    const int B       = in_sizes[0] / 4;     // 256
    const int n_total = in_sizes[3] / 9;     // 36864
    const int n_tiles = n_total / NCHUNK;    // 24 (exact: 24*1536 = 36864)
    const int b_grps  = B / BPB;             // 32

    dim3 g1(n_tiles, b_grps);
    k1_partials<<<g1, TPB, 0, stream>>>(cov, grids, (double*)d_ws, B);
    k2_finalize<<<(B + TPB - 1) / TPB, TPB, 0, stream>>>(
        gt, mode, cov, (const double*)d_ws, out, n_tiles, n_total, B);
}